// Round 4
// baseline (899.401 us; speedup 1.0000x reference)
//
#include <hip/hip_runtime.h>
#include <math.h>

// Problem constants (from reference)
constexpr int NE = 200000;   // edges
constexpr int ND = 120;      // node feature dim = 32 + 48 + 40

__global__ __launch_bounds__(256, 2) void fused_edge_kernel(
    const float* __restrict__ nodes,
    const int*   __restrict__ src,
    const int*   __restrict__ dst,
    const int*   __restrict__ batch_vec,
    const float* __restrict__ cell,
    const float* __restrict__ edge_shift,
    const float* __restrict__ pos,
    const float* __restrict__ angles,
    const float* __restrict__ cr_min,
    const float* __restrict__ cr_max,
    const float* __restrict__ W0,
    const float* __restrict__ W1,
    const float* __restrict__ W2,
    const float* __restrict__ ln_g,
    const float* __restrict__ ln_b,
    const float* __restrict__ rw1,
    const float* __restrict__ rb1,
    const float* __restrict__ rw2,
    const float* __restrict__ rb2,
    const float* __restrict__ mw1,
    const float* __restrict__ mb1,
    const float* __restrict__ mw2,
    const float* __restrict__ mb2,
    const float* __restrict__ ow,
    const float* __restrict__ ob,
    float* __restrict__ out)
{
    // k-major scratch: thread t's slot k at scr[k*256 + t] -> lanes hit
    // consecutive banks, conflict-free. Exactly 64 KB -> 2 blocks/CU.
    __shared__ float scr[64 * 256];
    const int tid = threadIdx.x;
    const int e = blockIdx.x * 256 + tid;
    if (e >= NE) return;

    const int is = src[e];
    const int id = dst[e];
    const float* __restrict__ x1 = nodes + (size_t)is * ND;
    const float* __restrict__ x2 = nodes + (size_t)id * ND;

    // ---------------- geometry: dist ----------------
    const int bg = batch_vec[is];
    const float* C = cell + bg * 9;
    const float sh0 = edge_shift[e * 3 + 0];
    const float sh1 = edge_shift[e * 3 + 1];
    const float sh2 = edge_shift[e * 3 + 2];
    const float rx = pos[id * 3 + 0] - pos[is * 3 + 0] + sh0 * C[0] + sh1 * C[3] + sh2 * C[6];
    const float ry = pos[id * 3 + 1] - pos[is * 3 + 1] + sh0 * C[1] + sh1 * C[4] + sh2 * C[7];
    const float rz = pos[id * 3 + 2] - pos[is * 3 + 2] + sh0 * C[2] + sh1 * C[5] + sh2 * C[8];
    const float dist = sqrtf(rx * rx + ry * ry + rz * rz);

    // ---------------- radial layer 1: h1 = silu(rbf @ rw1 + rb1) ----------------
    {
        float h1[64];
        #pragma unroll
        for (int j = 0; j < 64; ++j) h1[j] = rb1[j];
        #pragma unroll 1
        for (int i = 0; i < 64; ++i) {
            const float dd = dist - (5.0f / 63.0f) * (float)i;
            const float r = __expf(-10.0f * dd * dd);
            const float* __restrict__ wp = rw1 + i * 64;
            #pragma unroll
            for (int j = 0; j < 64; ++j) h1[j] = fmaf(r, wp[j], h1[j]);
        }
        #pragma unroll
        for (int j = 0; j < 64; ++j) {
            const float x = h1[j];
            scr[j * 256 + tid] = x / (1.0f + __expf(-x));   // silu -> LDS
        }
    }

    // ---------------- radial layer 2: emb = h1 @ rw2 + rb2 ----------------
    {
        float emb[64];
        #pragma unroll
        for (int j = 0; j < 64; ++j) emb[j] = rb2[j];
        #pragma unroll 1
        for (int k = 0; k < 64; ++k) {
            const float hk = scr[k * 256 + tid];
            const float* __restrict__ wp = rw2 + k * 64;
            #pragma unroll
            for (int j = 0; j < 64; ++j) emb[j] = fmaf(hk, wp[j], emb[j]);
        }
        #pragma unroll
        for (int j = 0; j < 64; ++j) scr[j * 256 + tid] = emb[j]; // emb -> LDS
    }

    // ---------------- MLP layer-1 partial: h2 = mb1 + emb@mw1[32:96] + scalars ----------------
    float h2[64];
    #pragma unroll
    for (int j = 0; j < 64; ++j) h2[j] = mb1[j];
    #pragma unroll 1
    for (int i = 0; i < 64; ++i) {
        const float ei = scr[i * 256 + tid];
        const float* __restrict__ wp = mw1 + (32 + i) * 64;
        #pragma unroll
        for (int j = 0; j < 64; ++j) h2[j] = fmaf(ei, wp[j], h2[j]);
    }
    {
        const float a  = angles[e];
        const float cm = cr_min[e];
        const float cx = cr_max[e];
        const float* __restrict__ wa = mw1 + 96 * 64;
        const float* __restrict__ wb = mw1 + 97 * 64;
        const float* __restrict__ wc = mw1 + 98 * 64;
        #pragma unroll
        for (int j = 0; j < 64; ++j)
            h2[j] += a * wa[j] + cm * wb[j] + cx * wc[j];
    }

    // ---------------- tensor product -> acc[32] ----------------
    float acc[32];
    #pragma unroll
    for (int w = 0; w < 32; ++w) acc[w] = 0.0f;

    { // L0 x L0 -> W0 (32,32,32)
        float b0[32];
        #pragma unroll
        for (int q = 0; q < 8; ++q) {
            const float4 f = *reinterpret_cast<const float4*>(x2 + 4 * q);
            b0[4 * q + 0] = f.x; b0[4 * q + 1] = f.y;
            b0[4 * q + 2] = f.z; b0[4 * q + 3] = f.w;
        }
        #pragma unroll 1
        for (int u = 0; u < 32; ++u) {
            const float a = x1[u];
            const float* __restrict__ wp = W0 + u * 32 * 32;
            #pragma unroll
            for (int v = 0; v < 32; ++v) {
                const float p = a * b0[v];
                #pragma unroll
                for (int w = 0; w < 32; ++w)
                    acc[w] = fmaf(p, wp[v * 32 + w], acc[w]);
            }
        }
    }
    { // L1 x L1 (dot over 3) -> W1 (16,16,32), * 1/sqrt(3)
        float bv[48];
        #pragma unroll
        for (int q = 0; q < 12; ++q) {
            const float4 f = *reinterpret_cast<const float4*>(x2 + 32 + 4 * q);
            bv[4 * q + 0] = f.x; bv[4 * q + 1] = f.y;
            bv[4 * q + 2] = f.z; bv[4 * q + 3] = f.w;
        }
        const float c1 = 0.57735026918962576f; // 1/sqrt(3)
        #pragma unroll 1
        for (int u = 0; u < 16; ++u) {
            const float a0 = x1[32 + 3 * u + 0];
            const float a1 = x1[32 + 3 * u + 1];
            const float a2 = x1[32 + 3 * u + 2];
            const float* __restrict__ wp = W1 + u * 16 * 32;
            #pragma unroll
            for (int v = 0; v < 16; ++v) {
                const float d = a0 * bv[3 * v + 0] + a1 * bv[3 * v + 1] + a2 * bv[3 * v + 2];
                const float p = d * c1;
                #pragma unroll
                for (int w = 0; w < 32; ++w)
                    acc[w] = fmaf(p, wp[v * 32 + w], acc[w]);
            }
        }
    }
    { // L2 x L2 (dot over 5) -> W2 (8,8,32), * 1/sqrt(5)
        float bt[40];
        #pragma unroll
        for (int q = 0; q < 10; ++q) {
            const float4 f = *reinterpret_cast<const float4*>(x2 + 80 + 4 * q);
            bt[4 * q + 0] = f.x; bt[4 * q + 1] = f.y;
            bt[4 * q + 2] = f.z; bt[4 * q + 3] = f.w;
        }
        const float c2 = 0.44721359549995794f; // 1/sqrt(5)
        #pragma unroll 1
        for (int u = 0; u < 8; ++u) {
            const float a0 = x1[80 + 5 * u + 0];
            const float a1 = x1[80 + 5 * u + 1];
            const float a2 = x1[80 + 5 * u + 2];
            const float a3 = x1[80 + 5 * u + 3];
            const float a4 = x1[80 + 5 * u + 4];
            const float* __restrict__ wp = W2 + u * 8 * 32;
            #pragma unroll
            for (int v = 0; v < 8; ++v) {
                const float d = a0 * bt[5 * v + 0] + a1 * bt[5 * v + 1] + a2 * bt[5 * v + 2]
                              + a3 * bt[5 * v + 3] + a4 * bt[5 * v + 4];
                const float p = d * c2;
                #pragma unroll
                for (int w = 0; w < 32; ++w)
                    acc[w] = fmaf(p, wp[v * 32 + w], acc[w]);
            }
        }
    }

    // ---------------- scale + layernorm ----------------
    const float tp_scale = 0.027277236685610633f; // 1/sqrt(32*32 + 16*16 + 8*8)
    #pragma unroll
    for (int w = 0; w < 32; ++w) acc[w] *= tp_scale;
    float mu = 0.0f;
    #pragma unroll
    for (int w = 0; w < 32; ++w) mu += acc[w];
    mu *= (1.0f / 32.0f);
    float var = 0.0f;
    #pragma unroll
    for (int w = 0; w < 32; ++w) { const float d = acc[w] - mu; var = fmaf(d, d, var); }
    var *= (1.0f / 32.0f);
    const float rstd = rsqrtf(var + 1e-5f);
    #pragma unroll
    for (int w = 0; w < 32; ++w) {
        const float mn = (acc[w] - mu) * rstd * ln_g[w] + ln_b[w];
        scr[w * 256 + tid] = mn; // mixednorm -> LDS (h1/emb region dead)
    }

    // ---------------- MLP layer-1: h2 += mn @ mw1[0:32], then silu ----------------
    #pragma unroll 1
    for (int i = 0; i < 32; ++i) {
        const float mi = scr[i * 256 + tid];
        const float* __restrict__ wp = mw1 + i * 64;
        #pragma unroll
        for (int j = 0; j < 64; ++j) h2[j] = fmaf(mi, wp[j], h2[j]);
    }
    #pragma unroll
    for (int j = 0; j < 64; ++j) {
        const float x = h2[j];
        scr[j * 256 + tid] = x / (1.0f + __expf(-x)); // silu(h2) -> LDS
    }

    // ---------------- MLP layer-2 + out ----------------
    float h3[64];
    #pragma unroll
    for (int j = 0; j < 64; ++j) h3[j] = mb2[j];
    #pragma unroll 1
    for (int k = 0; k < 64; ++k) {
        const float hk = scr[k * 256 + tid];
        const float* __restrict__ wp = mw2 + k * 64;
        #pragma unroll
        for (int j = 0; j < 64; ++j) h3[j] = fmaf(hk, wp[j], h3[j]);
    }
    float r = ob[0];
    #pragma unroll
    for (int j = 0; j < 64; ++j) {
        const float x = h3[j];
        const float s = x / (1.0f + __expf(-x)); // silu
        r = fmaf(s, ow[j], r);
    }
    out[e] = r;
}

extern "C" void kernel_launch(void* const* d_in, const int* in_sizes, int n_in,
                              void* d_out, int out_size, void* d_ws, size_t ws_size,
                              hipStream_t stream) {
    const float* nodes      = (const float*)d_in[0];
    const int*   src        = (const int*)  d_in[1];
    const int*   dst        = (const int*)  d_in[2];
    const int*   batch_vec  = (const int*)  d_in[3];
    const float* cell       = (const float*)d_in[4];
    const float* edge_shift = (const float*)d_in[5];
    const float* pos        = (const float*)d_in[6];
    const float* angles     = (const float*)d_in[7];
    const float* cr_min     = (const float*)d_in[8];
    const float* cr_max     = (const float*)d_in[9];
    const float* W0         = (const float*)d_in[10];
    const float* W1         = (const float*)d_in[11];
    const float* W2         = (const float*)d_in[12];
    const float* ln_g       = (const float*)d_in[13];
    const float* ln_b       = (const float*)d_in[14];
    const float* rw1        = (const float*)d_in[15];
    const float* rb1        = (const float*)d_in[16];
    const float* rw2        = (const float*)d_in[17];
    const float* rb2        = (const float*)d_in[18];
    const float* mw1        = (const float*)d_in[19];
    const float* mb1        = (const float*)d_in[20];
    const float* mw2        = (const float*)d_in[21];
    const float* mb2        = (const float*)d_in[22];
    const float* ow         = (const float*)d_in[23];
    const float* ob         = (const float*)d_in[24];
    float* out = (float*)d_out;

    const dim3 grid((NE + 255) / 256);
    const dim3 block(256);
    hipLaunchKernelGGL(fused_edge_kernel, grid, block, 0, stream,
                       nodes, src, dst, batch_vec, cell, edge_shift, pos,
                       angles, cr_min, cr_max, W0, W1, W2, ln_g, ln_b,
                       rw1, rb1, rw2, rb2, mw1, mb1, mw2, mb2, ow, ob, out);
}